// Round 2
// baseline (10101.231 us; speedup 1.0000x reference)
//
#include <hip/hip_runtime.h>
#include <hip/hip_bf16.h>

// Problem dims (fixed by reference)
#define BATCH 2
#define SEQ   2048
#define DIM   1024
#define IDIM  4096
#define NH    16
#define HD    64
#define TOK   (BATCH * SEQ)      // 4096 token rows

typedef __hip_bfloat16 bf16;

__device__ __forceinline__ float ldv(const float* p, size_t i) { return p[i]; }
__device__ __forceinline__ float ldv(const bf16*  p, size_t i) { return __bfloat162float(p[i]); }
__device__ __forceinline__ void  stv(float* p, size_t i, float v) { p[i] = v; }
__device__ __forceinline__ void  stv(bf16*  p, size_t i, float v) { p[i] = __float2bfloat16(v); }

// ---------------------------------------------------------------------------
// LayerNorm: one block (256 thr) per row of D=1024 (4 elems/thread).
// Input rows are fp32 (x or resid); output bf16 workspace.
// ---------------------------------------------------------------------------
__global__ __launch_bounds__(256) void ln_kernel(const float* __restrict__ in,
                                                 const float* __restrict__ w,
                                                 const float* __restrict__ b,
                                                 bf16* __restrict__ out) {
    const int row = blockIdx.x;
    const int tid = threadIdx.x;
    const float* xr = in + (size_t)row * DIM;

    float v[4], sum = 0.f, sq = 0.f;
#pragma unroll
    for (int i = 0; i < 4; i++) {
        float t = xr[tid + i * 256];
        v[i] = t; sum += t; sq += t * t;
    }
#pragma unroll
    for (int off = 32; off >= 1; off >>= 1) {
        sum += __shfl_xor(sum, off);
        sq  += __shfl_xor(sq,  off);
    }
    __shared__ float s1[4], s2[4];
    int wid = tid >> 6;
    if ((tid & 63) == 0) { s1[wid] = sum; s2[wid] = sq; }
    __syncthreads();
    sum = s1[0] + s1[1] + s1[2] + s1[3];
    sq  = s2[0] + s2[1] + s2[2] + s2[3];

    const float mean = sum * (1.f / DIM);
    const float var  = fmaxf(sq * (1.f / DIM) - mean * mean, 0.f);
    const float rstd = rsqrtf(var + 1e-12f);

    bf16* orow = out + (size_t)row * DIM;
#pragma unroll
    for (int i = 0; i < 4; i++) {
        int idx = tid + i * 256;
        orow[idx] = __float2bfloat16((v[i] - mean) * rstd * w[idx] + b[idx]);
    }
}

// ---------------------------------------------------------------------------
// Tiled GEMM: C[M,N] = A[M,K] @ W[K,N]  (+bias) (+epilogue)
// BM=BN=64, BK=16, 256 threads, 4x4 microtile, fp32 accumulate.
// A: TA (bf16 ws). W/bias: fp32 (model weights). aux/C: TX.
// MODE: 0 = none, 1 = exact GELU, 2 = C = acc*aux, 3 = C = acc+aux
// ---------------------------------------------------------------------------
#define BM 64
#define BN 64
#define BK 16

template<typename TA, typename TX, int MODE>
__global__ __launch_bounds__(256) void gemm_kernel(const TA* __restrict__ A,
                                                   const float* __restrict__ W,
                                                   const float* __restrict__ bias,
                                                   const TX* __restrict__ aux,
                                                   TX* __restrict__ C,
                                                   int M, int N, int K) {
    __shared__ alignas(16) float As[BK][BM + 4];
    __shared__ alignas(16) float Bs[BK][BN + 4];

    const int tid  = threadIdx.x;
    const int row0 = blockIdx.y * BM;
    const int col0 = blockIdx.x * BN;
    const int tx   = tid & 15;   // 16 cols of threads
    const int ty   = tid >> 4;   // 16 rows of threads

    float acc[4][4] = {{0.f}};

    for (int k0 = 0; k0 < K; k0 += BK) {
        // A tile: 64x16 = 1024 elems, 4 per thread, k fastest for coalescing
#pragma unroll
        for (int i = 0; i < 4; i++) {
            int lin = tid + i * 256;
            int ak = lin & (BK - 1);
            int am = lin >> 4;
            As[ak][am] = ldv(A, (size_t)(row0 + am) * K + k0 + ak);
        }
        // B tile: 16x64, n fastest (fully coalesced)
#pragma unroll
        for (int i = 0; i < 4; i++) {
            int lin = tid + i * 256;
            int bn = lin & (BN - 1);
            int bk = lin >> 6;
            Bs[bk][bn] = W[(size_t)(k0 + bk) * N + col0 + bn];
        }
        __syncthreads();

#pragma unroll
        for (int k = 0; k < BK; k++) {
            float a[4], b[4];
#pragma unroll
            for (int i = 0; i < 4; i++) a[i] = As[k][ty * 4 + i];
#pragma unroll
            for (int j = 0; j < 4; j++) b[j] = Bs[k][tx * 4 + j];
#pragma unroll
            for (int i = 0; i < 4; i++)
#pragma unroll
                for (int j = 0; j < 4; j++)
                    acc[i][j] += a[i] * b[j];
        }
        __syncthreads();
    }

#pragma unroll
    for (int i = 0; i < 4; i++) {
        int m = row0 + ty * 4 + i;
#pragma unroll
        for (int j = 0; j < 4; j++) {
            int n = col0 + tx * 4 + j;
            float c = acc[i][j];
            if (bias) c += bias[n];
            if (MODE == 1) {
                c = 0.5f * c * (1.f + erff(c * 0.70710678118654752f));
            } else if (MODE == 2) {
                c *= ldv(aux, (size_t)m * N + n);
            } else if (MODE == 3) {
                c += ldv(aux, (size_t)m * N + n);
            }
            stv(C, (size_t)m * N + n, c);
        }
    }
}

// ---------------------------------------------------------------------------
// Attention: one wave per query row. lane = head-dim element (HD == 64).
// Online softmax over all S keys. qkv layout: [TOK, 3*DIM] (q|k|v slices).
// ---------------------------------------------------------------------------
__global__ __launch_bounds__(256) void attn_kernel(const bf16* __restrict__ qkv,
                                                   const float* __restrict__ mask,
                                                   bf16* __restrict__ ctx) {
    const int gwave = (blockIdx.x * 256 + threadIdx.x) >> 6;  // B*NH*SEQ waves
    const int lane  = threadIdx.x & 63;
    const int q     = gwave & (SEQ - 1);
    const int bh    = gwave >> 11;
    const int h     = bh & (NH - 1);
    const int b     = bh >> 4;

    const size_t row_q = (size_t)(b * SEQ + q) * (3 * DIM);
    const float  qv    = __bfloat162float(qkv[row_q + h * HD + lane]) * 0.125f;  // 1/sqrt(64)

    const bf16*  kbase = qkv + (size_t)b * SEQ * (3 * DIM) + DIM     + h * HD + lane;
    const bf16*  vbase = qkv + (size_t)b * SEQ * (3 * DIM) + 2 * DIM + h * HD + lane;
    const float* mrow  = mask + (size_t)b * SEQ;

    float m = -1e30f, l = 0.f, o = 0.f;
    for (int j = 0; j < SEQ; j++) {
        float s = qv * __bfloat162float(kbase[(size_t)j * (3 * DIM)]);
#pragma unroll
        for (int off = 32; off >= 1; off >>= 1) s += __shfl_xor(s, off);
        s += mrow[j];

        float mn    = fmaxf(m, s);
        float alpha = __expf(m - mn);
        float p     = __expf(s - mn);
        l = l * alpha + p;
        o = o * alpha + p * __bfloat162float(vbase[(size_t)j * (3 * DIM)]);
        m = mn;
    }
    ctx[(size_t)(b * SEQ + q) * DIM + h * HD + lane] = __float2bfloat16(o / l);
}

// ---------------------------------------------------------------------------
// resid = attn_out + attn_ob + x   (fp32, writes d_out)
// ---------------------------------------------------------------------------
__global__ __launch_bounds__(256) void residual_kernel(const bf16* __restrict__ attn_out,
                                                       const float* __restrict__ bias,
                                                       const float* __restrict__ x,
                                                       float* __restrict__ out) {
    size_t i = (size_t)blockIdx.x * 256 + threadIdx.x;
    out[i] = __bfloat162float(attn_out[i]) + bias[i & (DIM - 1)] + x[i];
}

// ---------------------------------------------------------------------------
extern "C" void kernel_launch(void* const* d_in, const int* in_sizes, int n_in,
                              void* d_out, int out_size, void* d_ws, size_t ws_size,
                              hipStream_t stream) {
    const float* x        = (const float*)d_in[0];
    const float* mask     = (const float*)d_in[1];
    const float* norm_w   = (const float*)d_in[2];
    const float* norm_b   = (const float*)d_in[3];
    const float* qkvw     = (const float*)d_in[4];
    const float* qkvb     = (const float*)d_in[5];
    const float* attn_ow  = (const float*)d_in[6];
    const float* attn_ob  = (const float*)d_in[7];
    const float* attn_nw  = (const float*)d_in[8];
    const float* attn_nb  = (const float*)d_in[9];
    const float* inter_w  = (const float*)d_in[10];
    const float* inter_b  = (const float*)d_in[11];
    const float* inter_w1 = (const float*)d_in[12];
    const float* output_w = (const float*)d_in[13];
    const float* output_b = (const float*)d_in[14];

    float* out = (float*)d_out;
    bf16*  ws  = (bf16*)d_ws;

    const size_t TD = (size_t)TOK * DIM;  // 4M elements
    // bf16 workspace layout (peak 6*TD = 48 MB):
    bf16* ln1      = ws;                  // S0 [0,TD): ln1 -> ctx -> ln2
    bf16* qkv      = ws + TD;             // [TD,4TD): qkv; reused for inter
    bf16* ctx      = ws;
    bf16* ln2      = ws;
    bf16* inter    = ws + TD;             // [TD,5TD) (qkv dead by then)
    bf16* attn_out = ws + 5 * TD;         // [5TD,6TD)
    float* resid   = out;                 // residual lives in d_out (fp32)

    dim3 blk(256);

    // 1. ln1 = LN(x)
    ln_kernel<<<TOK, blk, 0, stream>>>(x, norm_w, norm_b, ln1);

    // 2. qkv = ln1 @ qkvw + qkvb           [4096, 3072]
    gemm_kernel<bf16, bf16, 0><<<dim3((3 * DIM) / BN, TOK / BM), blk, 0, stream>>>(
        ln1, qkvw, qkvb, nullptr, qkv, TOK, 3 * DIM, DIM);

    // 3. attention -> ctx [4096, 1024]    (overwrites ln1 slot; ln1 dead)
    attn_kernel<<<(BATCH * NH * SEQ) / 4, blk, 0, stream>>>(qkv, mask, ctx);

    // 4. attn_out = ctx @ attn_ow          [4096, 1024]
    gemm_kernel<bf16, bf16, 0><<<dim3(DIM / BN, TOK / BM), blk, 0, stream>>>(
        ctx, attn_ow, nullptr, nullptr, attn_out, TOK, DIM, DIM);

    // 5. resid = attn_out + attn_ob + x    (fp32, into d_out)
    residual_kernel<<<TD / 256, blk, 0, stream>>>(attn_out, attn_ob, x, resid);

    // 6. ln2 = LN(resid)                   (overwrites ctx slot; ctx dead)
    ln_kernel<<<TOK, blk, 0, stream>>>(resid, attn_nw, attn_nb, ln2);

    // 7. inter = gelu(ln2 @ inter_w + inter_b)   [4096, 4096]  (qkv slot dead)
    gemm_kernel<bf16, bf16, 1><<<dim3(IDIM / BN, TOK / BM), blk, 0, stream>>>(
        ln2, inter_w, inter_b, nullptr, inter, TOK, IDIM, DIM);

    // 8. inter = (attn_out @ inter_w1) * inter   (in-place gated product)
    gemm_kernel<bf16, bf16, 2><<<dim3(IDIM / BN, TOK / BM), blk, 0, stream>>>(
        attn_out, inter_w1, nullptr, inter, inter, TOK, IDIM, DIM);

    // 9. out = inter @ output_w + output_b + resid   (resid aliases d_out; safe:
    //    each element read once in epilogue by its owning thread before write)
    gemm_kernel<bf16, float, 3><<<dim3(DIM / BN, TOK / BM), blk, 0, stream>>>(
        inter, output_w, output_b, resid, out, TOK, DIM, IDIM);
}

// Round 3
// 2050.129 us; speedup vs baseline: 4.9271x; 4.9271x over previous
//
#include <hip/hip_runtime.h>
#include <hip/hip_bf16.h>

// Problem dims (fixed by reference)
#define BATCH 2
#define SEQ   2048
#define DIM   1024
#define IDIM  4096
#define NH    16
#define HD    64
#define TOK   (BATCH * SEQ)      // 4096 token rows

typedef __hip_bfloat16 bf16;

typedef short bf16x8_t __attribute__((ext_vector_type(8)));
typedef float f32x4_t  __attribute__((ext_vector_type(4)));

__device__ __forceinline__ float ldv(const float* p, size_t i) { return p[i]; }
__device__ __forceinline__ float ldv(const bf16*  p, size_t i) { return __bfloat162float(p[i]); }
__device__ __forceinline__ void  stv(float* p, size_t i, float v) { p[i] = v; }
__device__ __forceinline__ void  stv(bf16*  p, size_t i, float v) { p[i] = __float2bfloat16(v); }

// ---------------------------------------------------------------------------
// LayerNorm: one block (256 thr) per row of D=1024 (4 elems/thread).
// ---------------------------------------------------------------------------
__global__ __launch_bounds__(256) void ln_kernel(const float* __restrict__ in,
                                                 const float* __restrict__ w,
                                                 const float* __restrict__ b,
                                                 bf16* __restrict__ out) {
    const int row = blockIdx.x;
    const int tid = threadIdx.x;
    const float* xr = in + (size_t)row * DIM;

    float v[4], sum = 0.f, sq = 0.f;
#pragma unroll
    for (int i = 0; i < 4; i++) {
        float t = xr[tid + i * 256];
        v[i] = t; sum += t; sq += t * t;
    }
#pragma unroll
    for (int off = 32; off >= 1; off >>= 1) {
        sum += __shfl_xor(sum, off);
        sq  += __shfl_xor(sq,  off);
    }
    __shared__ float s1[4], s2[4];
    int wid = tid >> 6;
    if ((tid & 63) == 0) { s1[wid] = sum; s2[wid] = sq; }
    __syncthreads();
    sum = s1[0] + s1[1] + s1[2] + s1[3];
    sq  = s2[0] + s2[1] + s2[2] + s2[3];

    const float mean = sum * (1.f / DIM);
    const float var  = fmaxf(sq * (1.f / DIM) - mean * mean, 0.f);
    const float rstd = rsqrtf(var + 1e-12f);

    bf16* orow = out + (size_t)row * DIM;
#pragma unroll
    for (int i = 0; i < 4; i++) {
        int idx = tid + i * 256;
        orow[idx] = __float2bfloat16((v[i] - mean) * rstd * w[idx] + b[idx]);
    }
}

// ---------------------------------------------------------------------------
// Tiled GEMM: C[M,N] = A[M,K] @ W[K,N]  (+bias) (+epilogue)
// MODE: 0 = none, 1 = exact GELU, 2 = C = acc*aux, 3 = C = acc+aux
// ---------------------------------------------------------------------------
#define BM 64
#define BN 64
#define BK 16

template<typename TA, typename TX, int MODE>
__global__ __launch_bounds__(256) void gemm_kernel(const TA* __restrict__ A,
                                                   const float* __restrict__ W,
                                                   const float* __restrict__ bias,
                                                   const TX* __restrict__ aux,
                                                   TX* __restrict__ C,
                                                   int M, int N, int K) {
    __shared__ alignas(16) float As[BK][BM + 4];
    __shared__ alignas(16) float Bs[BK][BN + 4];

    const int tid  = threadIdx.x;
    const int row0 = blockIdx.y * BM;
    const int col0 = blockIdx.x * BN;
    const int tx   = tid & 15;
    const int ty   = tid >> 4;

    float acc[4][4] = {{0.f}};

    for (int k0 = 0; k0 < K; k0 += BK) {
#pragma unroll
        for (int i = 0; i < 4; i++) {
            int lin = tid + i * 256;
            int ak = lin & (BK - 1);
            int am = lin >> 4;
            As[ak][am] = ldv(A, (size_t)(row0 + am) * K + k0 + ak);
        }
#pragma unroll
        for (int i = 0; i < 4; i++) {
            int lin = tid + i * 256;
            int bn = lin & (BN - 1);
            int bk = lin >> 6;
            Bs[bk][bn] = W[(size_t)(k0 + bk) * N + col0 + bn];
        }
        __syncthreads();

#pragma unroll
        for (int k = 0; k < BK; k++) {
            float a[4], b[4];
#pragma unroll
            for (int i = 0; i < 4; i++) a[i] = As[k][ty * 4 + i];
#pragma unroll
            for (int j = 0; j < 4; j++) b[j] = Bs[k][tx * 4 + j];
#pragma unroll
            for (int i = 0; i < 4; i++)
#pragma unroll
                for (int j = 0; j < 4; j++)
                    acc[i][j] += a[i] * b[j];
        }
        __syncthreads();
    }

#pragma unroll
    for (int i = 0; i < 4; i++) {
        int m = row0 + ty * 4 + i;
#pragma unroll
        for (int j = 0; j < 4; j++) {
            int n = col0 + tx * 4 + j;
            float c = acc[i][j];
            if (bias) c += bias[n];
            if (MODE == 1) {
                c = 0.5f * c * (1.f + erff(c * 0.70710678118654752f));
            } else if (MODE == 2) {
                c *= ldv(aux, (size_t)m * N + n);
            } else if (MODE == 3) {
                c += ldv(aux, (size_t)m * N + n);
            }
            stv(C, (size_t)m * N + n, c);
        }
    }
}

// ---------------------------------------------------------------------------
// MFMA flash attention.
// Grid: (32 q-tiles, 32 bh). Block: 256 thr = 4 waves; wave owns 16 Q-rows.
// Loop over 32 chunks of 64 keys: stage K[key][dim] and Vt[dim][key] in LDS
// (rows padded to 72 bf16 = 144 B -> 2-way max bank aliasing on b128 = free),
// QK^T via 16x16x32 bf16 MFMA, online softmax in fp32, P through per-wave
// LDS (C-layout -> A-layout transform), PV via MFMA into fp32 C-frags.
// ---------------------------------------------------------------------------
#define KCH 64
#define LDP 72

__device__ __forceinline__ f32x4_t mfma16(bf16x8_t a, bf16x8_t b, f32x4_t c) {
    return __builtin_amdgcn_mfma_f32_16x16x32_bf16(a, b, c, 0, 0, 0);
}

__global__ __launch_bounds__(256) void attn_mfma_kernel(const bf16* __restrict__ qkv,
                                                        const float* __restrict__ mask,
                                                        bf16* __restrict__ ctx) {
    __shared__ alignas(16) bf16 Klds[KCH][LDP];     // [key][dim]
    __shared__ alignas(16) bf16 Vtlds[HD][LDP];     // [dim][key]
    __shared__ alignas(16) bf16 Plds[4][16][LDP];   // per-wave [row][key]

    const int tid  = threadIdx.x;
    const int w    = tid >> 6;        // wave 0..3
    const int lane = tid & 63;
    const int ln   = lane & 15;       // 16-group index
    const int qd   = lane >> 4;       // quad 0..3

    const int qtile = blockIdx.x;     // 0..31
    const int bh    = blockIdx.y;     // 0..31
    const int bb    = bh >> 4;
    const int h     = bh & 15;

    const bf16*  base = qkv + (size_t)bb * SEQ * (3 * DIM) + h * HD;
    const float* mrow = mask + (size_t)bb * SEQ;

    // Q fragments (A-layout), persistent across chunks
    const bf16* qrow = base + (size_t)(qtile * 64 + w * 16 + ln) * (3 * DIM);
    const bf16x8_t aq0 = *(const bf16x8_t*)(qrow + qd * 8);
    const bf16x8_t aq1 = *(const bf16x8_t*)(qrow + 32 + qd * 8);

    f32x4_t O[4] = {{0,0,0,0},{0,0,0,0},{0,0,0,0},{0,0,0,0}};
    float mi[4] = {-1e30f,-1e30f,-1e30f,-1e30f};
    float li[4] = {0.f,0.f,0.f,0.f};

    for (int c = 0; c < SEQ / KCH; c++) {
        const int k0 = c * KCH;
        __syncthreads();   // prior chunk's K/V reads done before overwrite

        // --- stage K chunk: 64 keys x 64 dims, b128 per thread x2 ---
#pragma unroll
        for (int i = 0; i < 2; i++) {
            int lin  = tid + i * 256;          // 0..511, 8 dims each
            int key  = lin >> 3;
            int doct = lin & 7;
            *(bf16x8_t*)&Klds[key][doct * 8] =
                *(const bf16x8_t*)(base + (size_t)(k0 + key) * (3 * DIM) + DIM + doct * 8);
        }
        // --- stage V transposed: Vt[dim][key], 4 keys per b64 write ---
#pragma unroll
        for (int p = 0; p < 4; p++) {
            int dim = tid & 63;
            int kg  = (tid >> 6) + p * 4;      // key group 0..15 (4 keys each)
            bf16 vv[4];
#pragma unroll
            for (int j = 0; j < 4; j++)
                vv[j] = base[(size_t)(k0 + kg * 4 + j) * (3 * DIM) + 2 * DIM + dim];
            *(float2*)&Vtlds[dim][kg * 4] = *(float2*)vv;
        }
        __syncthreads();

        // --- QK^T: S[ks] = Q(16x64) @ K^T(64x16) for 4 key-subtiles ---
        f32x4_t S[4];
#pragma unroll
        for (int ks = 0; ks < 4; ks++) {
            int key = ks * 16 + ln;
            bf16x8_t b0 = *(const bf16x8_t*)&Klds[key][qd * 8];
            bf16x8_t b1 = *(const bf16x8_t*)&Klds[key][32 + qd * 8];
            f32x4_t acc = {0,0,0,0};
            acc = mfma16(aq0, b0, acc);
            acc = mfma16(aq1, b1, acc);
            S[ks] = acc;
        }
        // scale + additive mask
#pragma unroll
        for (int ks = 0; ks < 4; ks++) {
            float mv = mrow[k0 + ks * 16 + ln];
#pragma unroll
            for (int r = 0; r < 4; r++) S[ks][r] = S[ks][r] * 0.125f + mv;
        }

        // --- online softmax (rows = qd*4+r, spread over 16 lanes) ---
        float t[4];
#pragma unroll
        for (int r = 0; r < 4; r++)
            t[r] = fmaxf(fmaxf(S[0][r], S[1][r]), fmaxf(S[2][r], S[3][r]));
#pragma unroll
        for (int off = 1; off <= 8; off <<= 1)
#pragma unroll
            for (int r = 0; r < 4; r++) t[r] = fmaxf(t[r], __shfl_xor(t[r], off));

        float al[4];
#pragma unroll
        for (int r = 0; r < 4; r++) {
            float mn = fmaxf(mi[r], t[r]);
            al[r] = __expf(mi[r] - mn);
            mi[r] = mn;
        }
#pragma unroll
        for (int ks = 0; ks < 4; ks++)
#pragma unroll
            for (int r = 0; r < 4; r++) S[ks][r] = __expf(S[ks][r] - mi[r]);

        float rs[4];
#pragma unroll
        for (int r = 0; r < 4; r++)
            rs[r] = (S[0][r] + S[1][r]) + (S[2][r] + S[3][r]);
#pragma unroll
        for (int off = 1; off <= 8; off <<= 1)
#pragma unroll
            for (int r = 0; r < 4; r++) rs[r] += __shfl_xor(rs[r], off);
#pragma unroll
        for (int r = 0; r < 4; r++) li[r] = li[r] * al[r] + rs[r];

        // rescale O
#pragma unroll
        for (int ns = 0; ns < 4; ns++)
#pragma unroll
            for (int r = 0; r < 4; r++) O[ns][r] *= al[r];

        // --- P: C-layout -> LDS -> A-layout ---
#pragma unroll
        for (int ks = 0; ks < 4; ks++)
#pragma unroll
            for (int r = 0; r < 4; r++)
                Plds[w][qd * 4 + r][ks * 16 + ln] = __float2bfloat16(S[ks][r]);
        __syncthreads();

        bf16x8_t pa0 = *(const bf16x8_t*)&Plds[w][ln][qd * 8];
        bf16x8_t pa1 = *(const bf16x8_t*)&Plds[w][ln][32 + qd * 8];

        // --- PV: O(16x64) += P(16x64) @ V(64x64) ---
#pragma unroll
        for (int ns = 0; ns < 4; ns++) {
            bf16x8_t v0 = *(const bf16x8_t*)&Vtlds[ns * 16 + ln][qd * 8];
            bf16x8_t v1 = *(const bf16x8_t*)&Vtlds[ns * 16 + ln][32 + qd * 8];
            O[ns] = mfma16(pa0, v0, O[ns]);
            O[ns] = mfma16(pa1, v1, O[ns]);
        }
    }

    // --- epilogue: ctx[token][h*64+dim] = O / l ---
#pragma unroll
    for (int r = 0; r < 4; r++) {
        int row = qd * 4 + r;
        bf16* orow = ctx + (size_t)(bb * SEQ + qtile * 64 + w * 16 + row) * DIM + h * HD;
        float inv = 1.f / li[r];
#pragma unroll
        for (int ns = 0; ns < 4; ns++)
            orow[ns * 16 + ln] = __float2bfloat16(O[ns][r] * inv);
    }
}

// ---------------------------------------------------------------------------
// resid = attn_out + attn_ob + x   (fp32, writes d_out)
// ---------------------------------------------------------------------------
__global__ __launch_bounds__(256) void residual_kernel(const bf16* __restrict__ attn_out,
                                                       const float* __restrict__ bias,
                                                       const float* __restrict__ x,
                                                       float* __restrict__ out) {
    size_t i = (size_t)blockIdx.x * 256 + threadIdx.x;
    out[i] = __bfloat162float(attn_out[i]) + bias[i & (DIM - 1)] + x[i];
}

// ---------------------------------------------------------------------------
extern "C" void kernel_launch(void* const* d_in, const int* in_sizes, int n_in,
                              void* d_out, int out_size, void* d_ws, size_t ws_size,
                              hipStream_t stream) {
    const float* x        = (const float*)d_in[0];
    const float* mask     = (const float*)d_in[1];
    const float* norm_w   = (const float*)d_in[2];
    const float* norm_b   = (const float*)d_in[3];
    const float* qkvw     = (const float*)d_in[4];
    const float* qkvb     = (const float*)d_in[5];
    const float* attn_ow  = (const float*)d_in[6];
    const float* attn_ob  = (const float*)d_in[7];
    const float* attn_nw  = (const float*)d_in[8];
    const float* attn_nb  = (const float*)d_in[9];
    const float* inter_w  = (const float*)d_in[10];
    const float* inter_b  = (const float*)d_in[11];
    const float* inter_w1 = (const float*)d_in[12];
    const float* output_w = (const float*)d_in[13];
    const float* output_b = (const float*)d_in[14];

    float* out = (float*)d_out;
    bf16*  ws  = (bf16*)d_ws;

    const size_t TD = (size_t)TOK * DIM;  // 4M elements
    bf16* ln1      = ws;                  // S0 [0,TD): ln1 -> ctx -> ln2
    bf16* qkv      = ws + TD;             // [TD,4TD): qkv; slot reused for inter
    bf16* ctx      = ws;
    bf16* ln2      = ws;
    bf16* inter    = ws + TD;             // [TD,5TD)
    bf16* attn_out = ws + 5 * TD;         // [5TD,6TD)
    float* resid   = out;

    dim3 blk(256);

    // 1. ln1 = LN(x)
    ln_kernel<<<TOK, blk, 0, stream>>>(x, norm_w, norm_b, ln1);

    // 2. qkv = ln1 @ qkvw + qkvb           [4096, 3072]
    gemm_kernel<bf16, bf16, 0><<<dim3((3 * DIM) / BN, TOK / BM), blk, 0, stream>>>(
        ln1, qkvw, qkvb, nullptr, qkv, TOK, 3 * DIM, DIM);

    // 3. MFMA flash attention -> ctx [4096, 1024]
    attn_mfma_kernel<<<dim3(SEQ / 64, BATCH * NH), blk, 0, stream>>>(qkv, mask, ctx);

    // 4. attn_out = ctx @ attn_ow          [4096, 1024]
    gemm_kernel<bf16, bf16, 0><<<dim3(DIM / BN, TOK / BM), blk, 0, stream>>>(
        ctx, attn_ow, nullptr, nullptr, attn_out, TOK, DIM, DIM);

    // 5. resid = attn_out + attn_ob + x    (fp32, into d_out)
    residual_kernel<<<TD / 256, blk, 0, stream>>>(attn_out, attn_ob, x, resid);

    // 6. ln2 = LN(resid)
    ln_kernel<<<TOK, blk, 0, stream>>>(resid, attn_nw, attn_nb, ln2);

    // 7. inter = gelu(ln2 @ inter_w + inter_b)   [4096, 4096]
    gemm_kernel<bf16, bf16, 1><<<dim3(IDIM / BN, TOK / BM), blk, 0, stream>>>(
        ln2, inter_w, inter_b, nullptr, inter, TOK, IDIM, DIM);

    // 8. inter = (attn_out @ inter_w1) * inter   (in-place gated product)
    gemm_kernel<bf16, bf16, 2><<<dim3(IDIM / BN, TOK / BM), blk, 0, stream>>>(
        attn_out, inter_w1, nullptr, inter, inter, TOK, IDIM, DIM);

    // 9. out = inter @ output_w + output_b + resid
    gemm_kernel<bf16, float, 3><<<dim3(DIM / BN, TOK / BM), blk, 0, stream>>>(
        inter, output_w, output_b, resid, out, TOK, DIM, IDIM);
}

// Round 4
// 595.310 us; speedup vs baseline: 16.9680x; 3.4438x over previous
//
#include <hip/hip_runtime.h>
#include <hip/hip_bf16.h>

// Problem dims (fixed by reference)
#define BATCH 2
#define SEQ   2048
#define DIM   1024
#define IDIM  4096
#define NH    16
#define HD    64
#define TOK   (BATCH * SEQ)      // 4096 token rows

typedef __hip_bfloat16 bf16;

typedef short bf16x8_t __attribute__((ext_vector_type(8)));
typedef float f32x4_t  __attribute__((ext_vector_type(4)));

__device__ __forceinline__ float ldv(const float* p, size_t i) { return p[i]; }
__device__ __forceinline__ float ldv(const bf16*  p, size_t i) { return __bfloat162float(p[i]); }
__device__ __forceinline__ void  stv(float* p, size_t i, float v) { p[i] = v; }
__device__ __forceinline__ void  stv(bf16*  p, size_t i, float v) { p[i] = __float2bfloat16(v); }

__device__ __forceinline__ f32x4_t mfma16(bf16x8_t a, bf16x8_t b, f32x4_t c) {
    return __builtin_amdgcn_mfma_f32_16x16x32_bf16(a, b, c, 0, 0, 0);
}

// async global->LDS, 16B per lane; LDS dest = wave-uniform base + lane*16
__device__ __forceinline__ void gload16(const bf16* g, bf16* l) {
    __builtin_amdgcn_global_load_lds(
        (const __attribute__((address_space(1))) void*)g,
        (__attribute__((address_space(3))) void*)l, 16, 0, 0);
}

// ---------------------------------------------------------------------------
// LayerNorm: one block (256 thr) per row of D=1024 (4 elems/thread).
// ---------------------------------------------------------------------------
__global__ __launch_bounds__(256) void ln_kernel(const float* __restrict__ in,
                                                 const float* __restrict__ w,
                                                 const float* __restrict__ b,
                                                 bf16* __restrict__ out) {
    const int row = blockIdx.x;
    const int tid = threadIdx.x;
    const float* xr = in + (size_t)row * DIM;

    float v[4], sum = 0.f, sq = 0.f;
#pragma unroll
    for (int i = 0; i < 4; i++) {
        float t = xr[tid + i * 256];
        v[i] = t; sum += t; sq += t * t;
    }
#pragma unroll
    for (int off = 32; off >= 1; off >>= 1) {
        sum += __shfl_xor(sum, off);
        sq  += __shfl_xor(sq,  off);
    }
    __shared__ float s1[4], s2[4];
    int wid = tid >> 6;
    if ((tid & 63) == 0) { s1[wid] = sum; s2[wid] = sq; }
    __syncthreads();
    sum = s1[0] + s1[1] + s1[2] + s1[3];
    sq  = s2[0] + s2[1] + s2[2] + s2[3];

    const float mean = sum * (1.f / DIM);
    const float var  = fmaxf(sq * (1.f / DIM) - mean * mean, 0.f);
    const float rstd = rsqrtf(var + 1e-12f);

    bf16* orow = out + (size_t)row * DIM;
#pragma unroll
    for (int i = 0; i < 4; i++) {
        int idx = tid + i * 256;
        orow[idx] = __float2bfloat16((v[i] - mean) * rstd * w[idx] + b[idx]);
    }
}

// ---------------------------------------------------------------------------
// Weight convert + transpose: W[K,N] fp32 -> Wt[N,K] bf16. 32x32 LDS tiles.
// ---------------------------------------------------------------------------
__global__ __launch_bounds__(256) void wconv_kernel(const float* __restrict__ W,
                                                    bf16* __restrict__ Wt,
                                                    int K, int N) {
    __shared__ float tile[32][33];
    const int tid = threadIdx.x;
    const int n0 = blockIdx.x * 32;
    const int k0 = blockIdx.y * 32;
    const int c = tid & 31;
    const int r = tid >> 5;           // 0..7
#pragma unroll
    for (int i = 0; i < 4; i++)
        tile[r + i * 8][c] = W[(size_t)(k0 + r + i * 8) * N + n0 + c];
    __syncthreads();
#pragma unroll
    for (int i = 0; i < 4; i++)
        Wt[(size_t)(n0 + r + i * 8) * K + k0 + c] = __float2bfloat16(tile[c][r + i * 8]);
}

// ---------------------------------------------------------------------------
// MFMA GEMM (m97 structure): C[M,N] = A[M,K] @ Wt[N,K]^T (+bias)(+epilogue)
// 128x128 tile, BK=32, 256 thr = 4 waves (2x2), 4x4 16x16x32 frags per wave.
// MODE: 0 = bias(optional), 1 = bias+GELU, 2 = acc*aux, 3 = bias+acc+aux
// ---------------------------------------------------------------------------
#define GBM 128
#define GBN 128
#define GBK 32

template<typename TX, int MODE>
__global__ __launch_bounds__(256) void mgemm_kernel(const bf16* __restrict__ A,
                                                    const bf16* __restrict__ Bt,
                                                    const float* __restrict__ bias,
                                                    const TX* __restrict__ aux,
                                                    TX* __restrict__ C,
                                                    int M, int N, int K) {
    __shared__ alignas(16) bf16 As[GBM][GBK];
    __shared__ alignas(16) bf16 Bs[GBN][GBK];

    const int tid  = threadIdx.x;
    const int w    = tid >> 6;
    const int lane = tid & 63;
    const int cl   = lane & 15;       // MFMA 16-group
    const int qd   = lane >> 4;       // quad
    const int wm   = w >> 1;
    const int wn   = w & 1;

    const int row0 = blockIdx.y * GBM;
    const int col0 = blockIdx.x * GBN;

    const int lrow = lane >> 2;       // staging row within 16-row group
    const int lkg  = lane & 3;        // staging k-group (8 elems)

    f32x4_t acc[4][4];
#pragma unroll
    for (int m = 0; m < 4; m++)
#pragma unroll
        for (int n = 0; n < 4; n++) acc[m][n] = {0.f, 0.f, 0.f, 0.f};

    for (int k0 = 0; k0 < K; k0 += GBK) {
        __syncthreads();
#pragma unroll
        for (int p = 0; p < 2; p++) {
            const int r16 = (w * 2 + p) * 16;
            gload16(A  + (size_t)(row0 + r16 + lrow) * K + k0 + lkg * 8, &As[r16][0]);
            gload16(Bt + (size_t)(col0 + r16 + lrow) * K + k0 + lkg * 8, &Bs[r16][0]);
        }
        __syncthreads();

        bf16x8_t af[4], bfr[4];
#pragma unroll
        for (int m = 0; m < 4; m++)
            af[m] = *(const bf16x8_t*)&As[wm * 64 + m * 16 + cl][qd * 8];
#pragma unroll
        for (int n = 0; n < 4; n++)
            bfr[n] = *(const bf16x8_t*)&Bs[wn * 64 + n * 16 + cl][qd * 8];
#pragma unroll
        for (int m = 0; m < 4; m++)
#pragma unroll
            for (int n = 0; n < 4; n++)
                acc[m][n] = mfma16(af[m], bfr[n], acc[m][n]);
    }

    // epilogue: C/D layout col=lane&15, row=qd*4+reg
#pragma unroll
    for (int m = 0; m < 4; m++) {
#pragma unroll
        for (int n = 0; n < 4; n++) {
            const int gc = col0 + wn * 64 + n * 16 + cl;
            const float bv = (MODE != 2 && bias) ? bias[gc] : 0.f;
#pragma unroll
            for (int r = 0; r < 4; r++) {
                const int gr = row0 + wm * 64 + m * 16 + qd * 4 + r;
                float c = acc[m][n][r] + bv;
                if (MODE == 1) {
                    c = 0.5f * c * (1.f + erff(c * 0.70710678118654752f));
                } else if (MODE == 2) {
                    c *= ldv(aux, (size_t)gr * N + gc);
                } else if (MODE == 3) {
                    c += ldv(aux, (size_t)gr * N + gc);
                }
                stv(C, (size_t)gr * N + gc, c);
            }
        }
    }
}

// ---------------------------------------------------------------------------
// MFMA flash attention (unchanged from round 3).
// ---------------------------------------------------------------------------
#define KCH 64
#define LDP 72

__global__ __launch_bounds__(256) void attn_mfma_kernel(const bf16* __restrict__ qkv,
                                                        const float* __restrict__ mask,
                                                        bf16* __restrict__ ctx) {
    __shared__ alignas(16) bf16 Klds[KCH][LDP];
    __shared__ alignas(16) bf16 Vtlds[HD][LDP];
    __shared__ alignas(16) bf16 Plds[4][16][LDP];

    const int tid  = threadIdx.x;
    const int w    = tid >> 6;
    const int lane = tid & 63;
    const int cl   = lane & 15;
    const int qd   = lane >> 4;

    const int qtile = blockIdx.x;
    const int bh    = blockIdx.y;
    const int bb    = bh >> 4;
    const int h     = bh & 15;

    const bf16*  base = qkv + (size_t)bb * SEQ * (3 * DIM) + h * HD;
    const float* mrow = mask + (size_t)bb * SEQ;

    const bf16* qrow = base + (size_t)(qtile * 64 + w * 16 + cl) * (3 * DIM);
    const bf16x8_t aq0 = *(const bf16x8_t*)(qrow + qd * 8);
    const bf16x8_t aq1 = *(const bf16x8_t*)(qrow + 32 + qd * 8);

    f32x4_t O[4] = {{0,0,0,0},{0,0,0,0},{0,0,0,0},{0,0,0,0}};
    float mi[4] = {-1e30f,-1e30f,-1e30f,-1e30f};
    float li[4] = {0.f,0.f,0.f,0.f};

    for (int c = 0; c < SEQ / KCH; c++) {
        const int k0 = c * KCH;
        __syncthreads();

#pragma unroll
        for (int i = 0; i < 2; i++) {
            int lin  = tid + i * 256;
            int key  = lin >> 3;
            int doct = lin & 7;
            *(bf16x8_t*)&Klds[key][doct * 8] =
                *(const bf16x8_t*)(base + (size_t)(k0 + key) * (3 * DIM) + DIM + doct * 8);
        }
#pragma unroll
        for (int p = 0; p < 4; p++) {
            int dim = tid & 63;
            int kg  = (tid >> 6) + p * 4;
            bf16 vv[4];
#pragma unroll
            for (int j = 0; j < 4; j++)
                vv[j] = base[(size_t)(k0 + kg * 4 + j) * (3 * DIM) + 2 * DIM + dim];
            *(float2*)&Vtlds[dim][kg * 4] = *(float2*)vv;
        }
        __syncthreads();

        f32x4_t S[4];
#pragma unroll
        for (int ks = 0; ks < 4; ks++) {
            int key = ks * 16 + cl;
            bf16x8_t b0 = *(const bf16x8_t*)&Klds[key][qd * 8];
            bf16x8_t b1 = *(const bf16x8_t*)&Klds[key][32 + qd * 8];
            f32x4_t s2 = {0,0,0,0};
            s2 = mfma16(aq0, b0, s2);
            s2 = mfma16(aq1, b1, s2);
            S[ks] = s2;
        }
#pragma unroll
        for (int ks = 0; ks < 4; ks++) {
            float mv = mrow[k0 + ks * 16 + cl];
#pragma unroll
            for (int r = 0; r < 4; r++) S[ks][r] = S[ks][r] * 0.125f + mv;
        }

        float t[4];
#pragma unroll
        for (int r = 0; r < 4; r++)
            t[r] = fmaxf(fmaxf(S[0][r], S[1][r]), fmaxf(S[2][r], S[3][r]));
#pragma unroll
        for (int off = 1; off <= 8; off <<= 1)
#pragma unroll
            for (int r = 0; r < 4; r++) t[r] = fmaxf(t[r], __shfl_xor(t[r], off));

        float al[4];
#pragma unroll
        for (int r = 0; r < 4; r++) {
            float mn = fmaxf(mi[r], t[r]);
            al[r] = __expf(mi[r] - mn);
            mi[r] = mn;
        }
#pragma unroll
        for (int ks = 0; ks < 4; ks++)
#pragma unroll
            for (int r = 0; r < 4; r++) S[ks][r] = __expf(S[ks][r] - mi[r]);

        float rs[4];
#pragma unroll
        for (int r = 0; r < 4; r++)
            rs[r] = (S[0][r] + S[1][r]) + (S[2][r] + S[3][r]);
#pragma unroll
        for (int off = 1; off <= 8; off <<= 1)
#pragma unroll
            for (int r = 0; r < 4; r++) rs[r] += __shfl_xor(rs[r], off);
#pragma unroll
        for (int r = 0; r < 4; r++) li[r] = li[r] * al[r] + rs[r];

#pragma unroll
        for (int ns = 0; ns < 4; ns++)
#pragma unroll
            for (int r = 0; r < 4; r++) O[ns][r] *= al[r];

#pragma unroll
        for (int ks = 0; ks < 4; ks++)
#pragma unroll
            for (int r = 0; r < 4; r++)
                Plds[w][qd * 4 + r][ks * 16 + cl] = __float2bfloat16(S[ks][r]);
        __syncthreads();

        bf16x8_t pa0 = *(const bf16x8_t*)&Plds[w][cl][qd * 8];
        bf16x8_t pa1 = *(const bf16x8_t*)&Plds[w][cl][32 + qd * 8];

#pragma unroll
        for (int ns = 0; ns < 4; ns++) {
            bf16x8_t v0 = *(const bf16x8_t*)&Vtlds[ns * 16 + cl][qd * 8];
            bf16x8_t v1 = *(const bf16x8_t*)&Vtlds[ns * 16 + cl][32 + qd * 8];
            O[ns] = mfma16(pa0, v0, O[ns]);
            O[ns] = mfma16(pa1, v1, O[ns]);
        }
    }

#pragma unroll
    for (int r = 0; r < 4; r++) {
        int row = qd * 4 + r;
        bf16* orow = ctx + (size_t)(bb * SEQ + qtile * 64 + w * 16 + row) * DIM + h * HD;
        float inv = 1.f / li[r];
#pragma unroll
        for (int ns = 0; ns < 4; ns++)
            orow[ns * 16 + cl] = __float2bfloat16(O[ns][r] * inv);
    }
}

// ---------------------------------------------------------------------------
// resid = attn_out + attn_ob + x   (fp32, writes d_out)
// ---------------------------------------------------------------------------
__global__ __launch_bounds__(256) void residual_kernel(const bf16* __restrict__ attn_out,
                                                       const float* __restrict__ bias,
                                                       const float* __restrict__ x,
                                                       float* __restrict__ out) {
    size_t i = (size_t)blockIdx.x * 256 + threadIdx.x;
    out[i] = __bfloat162float(attn_out[i]) + bias[i & (DIM - 1)] + x[i];
}

// ---------------------------------------------------------------------------
extern "C" void kernel_launch(void* const* d_in, const int* in_sizes, int n_in,
                              void* d_out, int out_size, void* d_ws, size_t ws_size,
                              hipStream_t stream) {
    const float* x        = (const float*)d_in[0];
    const float* mask     = (const float*)d_in[1];
    const float* norm_w   = (const float*)d_in[2];
    const float* norm_b   = (const float*)d_in[3];
    const float* qkvw     = (const float*)d_in[4];
    const float* qkvb     = (const float*)d_in[5];
    const float* attn_ow  = (const float*)d_in[6];
    const float* attn_ob  = (const float*)d_in[7];
    const float* attn_nw  = (const float*)d_in[8];
    const float* attn_nb  = (const float*)d_in[9];
    const float* inter_w  = (const float*)d_in[10];
    const float* inter_b  = (const float*)d_in[11];
    const float* inter_w1 = (const float*)d_in[12];
    const float* output_w = (const float*)d_in[13];
    const float* output_b = (const float*)d_in[14];

    float* out = (float*)d_out;
    bf16*  ws  = (bf16*)d_ws;

    const size_t M1 = 1024 * 1024;
    // ws layout (bf16 elems), peak 36M = 72 MB. Liveness-checked overlaps:
    //  [0,4M)    ln1 / ctx / ln2
    //  [4M,16M)  qkv (steps 2-3); [4M,20M) inter (steps 7-9)
    //  [16M,19M) qkvw_t  (steps 0-2; inside inter region, dead before step 7)
    //  [19M,20M) attn_owt (steps 0-4; same)
    //  [20M,24M) attn_out (steps 4-8)
    //  [24M,28M) inter_w_t  [28M,32M) inter_w1_t  [32M,36M) output_w_t
    bf16* ln_s      = ws;
    bf16* qkv       = ws + 4 * M1;
    bf16* inter     = ws + 4 * M1;
    bf16* qkvw_t    = ws + 16 * M1;
    bf16* attn_owt  = ws + 19 * M1;
    bf16* attn_out  = ws + 20 * M1;
    bf16* inter_wt  = ws + 24 * M1;
    bf16* inter_w1t = ws + 28 * M1;
    bf16* output_wt = ws + 32 * M1;
    float* resid    = out;

    dim3 blk(256);

    // 0. weight convert+transpose (fp32 [K,N] -> bf16 [N,K])
    wconv_kernel<<<dim3(3072 / 32, 1024 / 32), blk, 0, stream>>>(qkvw,     qkvw_t,    1024, 3072);
    wconv_kernel<<<dim3(1024 / 32, 1024 / 32), blk, 0, stream>>>(attn_ow,  attn_owt,  1024, 1024);
    wconv_kernel<<<dim3(4096 / 32, 1024 / 32), blk, 0, stream>>>(inter_w,  inter_wt,  1024, 4096);
    wconv_kernel<<<dim3(4096 / 32, 1024 / 32), blk, 0, stream>>>(inter_w1, inter_w1t, 1024, 4096);
    wconv_kernel<<<dim3(1024 / 32, 4096 / 32), blk, 0, stream>>>(output_w, output_wt, 4096, 1024);

    // 1. ln1 = LN(x)
    ln_kernel<<<TOK, blk, 0, stream>>>(x, norm_w, norm_b, ln_s);

    // 2. qkv = ln1 @ qkvw + qkvb           [4096, 3072]
    mgemm_kernel<bf16, 0><<<dim3(3072 / GBN, TOK / GBM), blk, 0, stream>>>(
        ln_s, qkvw_t, qkvb, (const bf16*)nullptr, qkv, TOK, 3 * DIM, DIM);

    // 3. MFMA flash attention -> ctx (reuses ln slot)
    attn_mfma_kernel<<<dim3(SEQ / 64, BATCH * NH), blk, 0, stream>>>(qkv, mask, ln_s);

    // 4. attn_out = ctx @ attn_ow          [4096, 1024], NO bias
    mgemm_kernel<bf16, 0><<<dim3(DIM / GBN, TOK / GBM), blk, 0, stream>>>(
        ln_s, attn_owt, (const float*)nullptr, (const bf16*)nullptr, attn_out, TOK, DIM, DIM);

    // 5. resid = attn_out + attn_ob + x    (fp32, into d_out)
    residual_kernel<<<(TOK * DIM) / 256, blk, 0, stream>>>(attn_out, attn_ob, x, resid);

    // 6. ln2 = LN(resid)
    ln_kernel<<<TOK, blk, 0, stream>>>(resid, attn_nw, attn_nb, ln_s);

    // 7. inter = gelu(ln2 @ inter_w + inter_b)   [4096, 4096]
    mgemm_kernel<bf16, 1><<<dim3(IDIM / GBN, TOK / GBM), blk, 0, stream>>>(
        ln_s, inter_wt, inter_b, (const bf16*)nullptr, inter, TOK, IDIM, DIM);

    // 8. inter = (attn_out @ inter_w1) * inter   (in-place gated product)
    mgemm_kernel<bf16, 2><<<dim3(IDIM / GBN, TOK / GBM), blk, 0, stream>>>(
        attn_out, inter_w1t, (const float*)nullptr, inter, inter, TOK, IDIM, DIM);

    // 9. out = inter @ output_w + output_b + resid  (resid aliases out; each
    //    element read by its owning thread before write — safe)
    mgemm_kernel<float, 3><<<dim3(DIM / GBN, TOK / GBM), blk, 0, stream>>>(
        inter, output_wt, output_b, resid, out, TOK, DIM, IDIM);
}

// Round 5
// 559.966 us; speedup vs baseline: 18.0390x; 1.0631x over previous
//
#include <hip/hip_runtime.h>
#include <hip/hip_bf16.h>

// Problem dims (fixed by reference)
#define BATCH 2
#define SEQ   2048
#define DIM   1024
#define IDIM  4096
#define NH    16
#define HD    64
#define TOK   (BATCH * SEQ)      // 4096 token rows

typedef __hip_bfloat16 bf16;

typedef short bf16x8_t __attribute__((ext_vector_type(8)));
typedef float f32x4_t  __attribute__((ext_vector_type(4)));

__device__ __forceinline__ float ldv(const float* p, size_t i) { return p[i]; }
__device__ __forceinline__ float ldv(const bf16*  p, size_t i) { return __bfloat162float(p[i]); }
__device__ __forceinline__ void  stv(float* p, size_t i, float v) { p[i] = v; }
__device__ __forceinline__ void  stv(bf16*  p, size_t i, float v) { p[i] = __float2bfloat16(v); }

__device__ __forceinline__ f32x4_t mfma16(bf16x8_t a, bf16x8_t b, f32x4_t c) {
    return __builtin_amdgcn_mfma_f32_16x16x32_bf16(a, b, c, 0, 0, 0);
}

// async global->LDS, 16B per lane; LDS dest = wave-uniform base + lane*16
__device__ __forceinline__ void gload16(const bf16* g, bf16* l) {
    __builtin_amdgcn_global_load_lds(
        (const __attribute__((address_space(1))) void*)g,
        (__attribute__((address_space(3))) void*)l, 16, 0, 0);
}

// ---------------------------------------------------------------------------
// LayerNorm: one block (256 thr) per row of D=1024 (4 elems/thread).
// ---------------------------------------------------------------------------
__global__ __launch_bounds__(256) void ln_kernel(const float* __restrict__ in,
                                                 const float* __restrict__ w,
                                                 const float* __restrict__ b,
                                                 bf16* __restrict__ out) {
    const int row = blockIdx.x;
    const int tid = threadIdx.x;
    const float* xr = in + (size_t)row * DIM;

    float v[4], sum = 0.f, sq = 0.f;
#pragma unroll
    for (int i = 0; i < 4; i++) {
        float t = xr[tid + i * 256];
        v[i] = t; sum += t; sq += t * t;
    }
#pragma unroll
    for (int off = 32; off >= 1; off >>= 1) {
        sum += __shfl_xor(sum, off);
        sq  += __shfl_xor(sq,  off);
    }
    __shared__ float s1[4], s2[4];
    int wid = tid >> 6;
    if ((tid & 63) == 0) { s1[wid] = sum; s2[wid] = sq; }
    __syncthreads();
    sum = s1[0] + s1[1] + s1[2] + s1[3];
    sq  = s2[0] + s2[1] + s2[2] + s2[3];

    const float mean = sum * (1.f / DIM);
    const float var  = fmaxf(sq * (1.f / DIM) - mean * mean, 0.f);
    const float rstd = rsqrtf(var + 1e-12f);

    bf16* orow = out + (size_t)row * DIM;
#pragma unroll
    for (int i = 0; i < 4; i++) {
        int idx = tid + i * 256;
        orow[idx] = __float2bfloat16((v[i] - mean) * rstd * w[idx] + b[idx]);
    }
}

// ---------------------------------------------------------------------------
// Weight convert + transpose: W[K,N] fp32 -> Wt[N,K] bf16. 32x32 LDS tiles.
// ---------------------------------------------------------------------------
__global__ __launch_bounds__(256) void wconv_kernel(const float* __restrict__ W,
                                                    bf16* __restrict__ Wt,
                                                    int K, int N) {
    __shared__ float tile[32][33];
    const int tid = threadIdx.x;
    const int n0 = blockIdx.x * 32;
    const int k0 = blockIdx.y * 32;
    const int c = tid & 31;
    const int r = tid >> 5;           // 0..7
#pragma unroll
    for (int i = 0; i < 4; i++)
        tile[r + i * 8][c] = W[(size_t)(k0 + r + i * 8) * N + n0 + c];
    __syncthreads();
#pragma unroll
    for (int i = 0; i < 4; i++)
        Wt[(size_t)(n0 + r + i * 8) * K + k0 + c] = __float2bfloat16(tile[c][r + i * 8]);
}

// ---------------------------------------------------------------------------
// MFMA GEMM (m97 structure): C[M,N] = A[M,K] @ Wt[N,K]^T (+bias)(+epilogue)
// 128x128 tile, BK=32, 256 thr = 4 waves (2x2), 4x4 16x16x32 frags per wave.
// MODE: 0 = bias(optional), 1 = bias+GELU, 2 = acc*aux, 3 = bias+acc+aux,
//       4 = dual: C (bf16) = acc;  C2 (fp32) = acc + bias2 + xin  (residual)
// ---------------------------------------------------------------------------
#define GBM 128
#define GBN 128
#define GBK 32

template<typename TX, int MODE>
__global__ __launch_bounds__(256) void mgemm_kernel(const bf16* __restrict__ A,
                                                    const bf16* __restrict__ Bt,
                                                    const float* __restrict__ bias,
                                                    const TX* __restrict__ aux,
                                                    TX* __restrict__ C,
                                                    const float* __restrict__ bias2,
                                                    const float* __restrict__ xin,
                                                    float* __restrict__ C2,
                                                    int M, int N, int K) {
    __shared__ alignas(16) bf16 As[GBM][GBK];
    __shared__ alignas(16) bf16 Bs[GBN][GBK];

    const int tid  = threadIdx.x;
    const int w    = tid >> 6;
    const int lane = tid & 63;
    const int cl   = lane & 15;       // MFMA 16-group
    const int qd   = lane >> 4;       // quad
    const int wm   = w >> 1;
    const int wn   = w & 1;

    const int row0 = blockIdx.y * GBM;
    const int col0 = blockIdx.x * GBN;

    const int lrow = lane >> 2;       // staging row within 16-row group
    const int lkg  = lane & 3;        // staging k-group (8 elems)

    f32x4_t acc[4][4];
#pragma unroll
    for (int m = 0; m < 4; m++)
#pragma unroll
        for (int n = 0; n < 4; n++) acc[m][n] = {0.f, 0.f, 0.f, 0.f};

    for (int k0 = 0; k0 < K; k0 += GBK) {
        __syncthreads();
#pragma unroll
        for (int p = 0; p < 2; p++) {
            const int r16 = (w * 2 + p) * 16;
            gload16(A  + (size_t)(row0 + r16 + lrow) * K + k0 + lkg * 8, &As[r16][0]);
            gload16(Bt + (size_t)(col0 + r16 + lrow) * K + k0 + lkg * 8, &Bs[r16][0]);
        }
        __syncthreads();

        bf16x8_t af[4], bfr[4];
#pragma unroll
        for (int m = 0; m < 4; m++)
            af[m] = *(const bf16x8_t*)&As[wm * 64 + m * 16 + cl][qd * 8];
#pragma unroll
        for (int n = 0; n < 4; n++)
            bfr[n] = *(const bf16x8_t*)&Bs[wn * 64 + n * 16 + cl][qd * 8];
#pragma unroll
        for (int m = 0; m < 4; m++)
#pragma unroll
            for (int n = 0; n < 4; n++)
                acc[m][n] = mfma16(af[m], bfr[n], acc[m][n]);
    }

    // epilogue: C/D layout col=lane&15, row=qd*4+reg
#pragma unroll
    for (int m = 0; m < 4; m++) {
#pragma unroll
        for (int n = 0; n < 4; n++) {
            const int gc = col0 + wn * 64 + n * 16 + cl;
            const float bv = (MODE != 2 && MODE != 4 && bias) ? bias[gc] : 0.f;
#pragma unroll
            for (int r = 0; r < 4; r++) {
                const int gr = row0 + wm * 64 + m * 16 + qd * 4 + r;
                float c = acc[m][n][r] + bv;
                if (MODE == 1) {
                    c = 0.5f * c * (1.f + erff(c * 0.70710678118654752f));
                } else if (MODE == 2) {
                    c *= ldv(aux, (size_t)gr * N + gc);
                } else if (MODE == 3) {
                    c += ldv(aux, (size_t)gr * N + gc);
                }
                stv(C, (size_t)gr * N + gc, c);
                if (MODE == 4) {
                    C2[(size_t)gr * N + gc] = c + bias2[gc] + xin[(size_t)gr * N + gc];
                }
            }
        }
    }
}

// ---------------------------------------------------------------------------
// MFMA flash attention.
// Grid (32 qtiles, 32 bh), 4 waves; wave owns 16 Q rows. 64-key chunks.
// V staged transposed with conflict-free pattern; l via ones-MFMA.
// ---------------------------------------------------------------------------
#define KCH 64
#define LDP 72

__global__ __launch_bounds__(256) void attn_mfma_kernel(const bf16* __restrict__ qkv,
                                                        const float* __restrict__ mask,
                                                        bf16* __restrict__ ctx) {
    __shared__ alignas(16) bf16 Klds[KCH][LDP];
    __shared__ alignas(16) bf16 Vtlds[HD][LDP];
    __shared__ alignas(16) bf16 Plds[4][16][LDP];

    const int tid  = threadIdx.x;
    const int w    = tid >> 6;
    const int lane = tid & 63;
    const int cl   = lane & 15;
    const int qd   = lane >> 4;

    const int qtile = blockIdx.x;
    const int bh    = blockIdx.y;
    const int bb    = bh >> 4;
    const int h     = bh & 15;

    const bf16*  base = qkv + (size_t)bb * SEQ * (3 * DIM) + h * HD;
    const float* mrow = mask + (size_t)bb * SEQ;

    const bf16* qrow = base + (size_t)(qtile * 64 + w * 16 + cl) * (3 * DIM);
    const bf16x8_t aq0 = *(const bf16x8_t*)(qrow + qd * 8);
    const bf16x8_t aq1 = *(const bf16x8_t*)(qrow + 32 + qd * 8);

    const bf16x8_t onesv = {0x3F80, 0x3F80, 0x3F80, 0x3F80,
                            0x3F80, 0x3F80, 0x3F80, 0x3F80};   // bf16 1.0 x8

    f32x4_t O[4] = {{0,0,0,0},{0,0,0,0},{0,0,0,0},{0,0,0,0}};
    float mi[4] = {-1e30f,-1e30f,-1e30f,-1e30f};
    float li[4] = {0.f,0.f,0.f,0.f};

    for (int c = 0; c < SEQ / KCH; c++) {
        const int k0 = c * KCH;
        __syncthreads();   // prior chunk's K/V/P reads done before overwrite

        // --- stage K chunk: b128 per lane, [key][dim], coalesced ---
#pragma unroll
        for (int i = 0; i < 2; i++) {
            int lin  = tid + i * 256;
            int key  = lin >> 3;
            int doct = lin & 7;
            *(bf16x8_t*)&Klds[key][doct * 8] =
                *(const bf16x8_t*)(base + (size_t)(k0 + key) * (3 * DIM) + DIM + doct * 8);
        }
        // --- stage V transposed, conflict-free: key = lane, dg wave-uniform.
        //     Write instr j: row dg*8+j uniform, col = lane -> contiguous 128B.
#pragma unroll
        for (int p = 0; p < 2; p++) {
            const int key = lane;
            const int dg  = w + p * 4;          // 0..7
            bf16x8_t vv = *(const bf16x8_t*)(base + (size_t)(k0 + key) * (3 * DIM)
                                             + 2 * DIM + dg * 8);
#pragma unroll
            for (int j = 0; j < 8; j++)
                ((short*)&Vtlds[dg * 8 + j][0])[key] = vv[j];
        }
        __syncthreads();

        // --- QK^T ---
        f32x4_t S[4];
#pragma unroll
        for (int ks = 0; ks < 4; ks++) {
            int key = ks * 16 + cl;
            bf16x8_t b0 = *(const bf16x8_t*)&Klds[key][qd * 8];
            bf16x8_t b1 = *(const bf16x8_t*)&Klds[key][32 + qd * 8];
            f32x4_t s2 = {0,0,0,0};
            s2 = mfma16(aq0, b0, s2);
            s2 = mfma16(aq1, b1, s2);
            S[ks] = s2;
        }
#pragma unroll
        for (int ks = 0; ks < 4; ks++) {
            float mv = mrow[k0 + ks * 16 + cl];
#pragma unroll
            for (int r = 0; r < 4; r++) S[ks][r] = S[ks][r] * 0.125f + mv;
        }

        // --- online max (16-lane shuffle reduce) ---
        float t[4];
#pragma unroll
        for (int r = 0; r < 4; r++)
            t[r] = fmaxf(fmaxf(S[0][r], S[1][r]), fmaxf(S[2][r], S[3][r]));
#pragma unroll
        for (int off = 1; off <= 8; off <<= 1)
#pragma unroll
            for (int r = 0; r < 4; r++) t[r] = fmaxf(t[r], __shfl_xor(t[r], off));

        float al[4];
#pragma unroll
        for (int r = 0; r < 4; r++) {
            float mn = fmaxf(mi[r], t[r]);
            al[r] = __expf(mi[r] - mn);
            mi[r] = mn;
        }
#pragma unroll
        for (int ks = 0; ks < 4; ks++)
#pragma unroll
            for (int r = 0; r < 4; r++) S[ks][r] = __expf(S[ks][r] - mi[r]);

        // --- P: C-layout -> LDS -> A-layout ---
#pragma unroll
        for (int ks = 0; ks < 4; ks++)
#pragma unroll
            for (int r = 0; r < 4; r++)
                Plds[w][qd * 4 + r][ks * 16 + cl] = __float2bfloat16(S[ks][r]);
        __syncthreads();

        bf16x8_t pa0 = *(const bf16x8_t*)&Plds[w][cl][qd * 8];
        bf16x8_t pa1 = *(const bf16x8_t*)&Plds[w][cl][32 + qd * 8];

        // --- l row-sum via ones-MFMA (all 16 cols identical = broadcast) ---
        f32x4_t lsum = {0,0,0,0};
        lsum = mfma16(pa0, onesv, lsum);
        lsum = mfma16(pa1, onesv, lsum);
#pragma unroll
        for (int r = 0; r < 4; r++) li[r] = li[r] * al[r] + lsum[r];

        // rescale O
#pragma unroll
        for (int ns = 0; ns < 4; ns++)
#pragma unroll
            for (int r = 0; r < 4; r++) O[ns][r] *= al[r];

        // --- PV ---
#pragma unroll
        for (int ns = 0; ns < 4; ns++) {
            bf16x8_t v0 = *(const bf16x8_t*)&Vtlds[ns * 16 + cl][qd * 8];
            bf16x8_t v1 = *(const bf16x8_t*)&Vtlds[ns * 16 + cl][32 + qd * 8];
            O[ns] = mfma16(pa0, v0, O[ns]);
            O[ns] = mfma16(pa1, v1, O[ns]);
        }
    }

#pragma unroll
    for (int r = 0; r < 4; r++) {
        int row = qd * 4 + r;
        bf16* orow = ctx + (size_t)(bb * SEQ + qtile * 64 + w * 16 + row) * DIM + h * HD;
        float inv = 1.f / li[r];
#pragma unroll
        for (int ns = 0; ns < 4; ns++)
            orow[ns * 16 + cl] = __float2bfloat16(O[ns][r] * inv);
    }
}

// ---------------------------------------------------------------------------
extern "C" void kernel_launch(void* const* d_in, const int* in_sizes, int n_in,
                              void* d_out, int out_size, void* d_ws, size_t ws_size,
                              hipStream_t stream) {
    const float* x        = (const float*)d_in[0];
    const float* mask     = (const float*)d_in[1];
    const float* norm_w   = (const float*)d_in[2];
    const float* norm_b   = (const float*)d_in[3];
    const float* qkvw     = (const float*)d_in[4];
    const float* qkvb     = (const float*)d_in[5];
    const float* attn_ow  = (const float*)d_in[6];
    const float* attn_ob  = (const float*)d_in[7];
    const float* attn_nw  = (const float*)d_in[8];
    const float* attn_nb  = (const float*)d_in[9];
    const float* inter_w  = (const float*)d_in[10];
    const float* inter_b  = (const float*)d_in[11];
    const float* inter_w1 = (const float*)d_in[12];
    const float* output_w = (const float*)d_in[13];
    const float* output_b = (const float*)d_in[14];

    float* out = (float*)d_out;
    bf16*  ws  = (bf16*)d_ws;

    const size_t M1 = 1024 * 1024;
    // ws layout (bf16 elems), peak 36M = 72 MB. Liveness-checked overlaps:
    //  [0,4M)    ln1 / ctx / ln2
    //  [4M,16M)  qkv (steps 2-3); [4M,20M) inter (steps 7-9)
    //  [16M,19M) qkvw_t  (steps 0-2; inside inter region, dead before step 7)
    //  [19M,20M) attn_owt (steps 0-4; same)
    //  [20M,24M) attn_out (steps 4-8)
    //  [24M,28M) inter_w_t  [28M,32M) inter_w1_t  [32M,36M) output_w_t
    bf16* ln_s      = ws;
    bf16* qkv       = ws + 4 * M1;
    bf16* inter     = ws + 4 * M1;
    bf16* qkvw_t    = ws + 16 * M1;
    bf16* attn_owt  = ws + 19 * M1;
    bf16* attn_out  = ws + 20 * M1;
    bf16* inter_wt  = ws + 24 * M1;
    bf16* inter_w1t = ws + 28 * M1;
    bf16* output_wt = ws + 32 * M1;
    float* resid    = out;

    dim3 blk(256);

    // 0. weight convert+transpose (fp32 [K,N] -> bf16 [N,K])
    wconv_kernel<<<dim3(3072 / 32, 1024 / 32), blk, 0, stream>>>(qkvw,     qkvw_t,    1024, 3072);
    wconv_kernel<<<dim3(1024 / 32, 1024 / 32), blk, 0, stream>>>(attn_ow,  attn_owt,  1024, 1024);
    wconv_kernel<<<dim3(4096 / 32, 1024 / 32), blk, 0, stream>>>(inter_w,  inter_wt,  1024, 4096);
    wconv_kernel<<<dim3(4096 / 32, 1024 / 32), blk, 0, stream>>>(inter_w1, inter_w1t, 1024, 4096);
    wconv_kernel<<<dim3(1024 / 32, 4096 / 32), blk, 0, stream>>>(output_w, output_wt, 4096, 1024);

    // 1. ln1 = LN(x)
    ln_kernel<<<TOK, blk, 0, stream>>>(x, norm_w, norm_b, ln_s);

    // 2. qkv = ln1 @ qkvw + qkvb           [4096, 3072]
    mgemm_kernel<bf16, 0><<<dim3(3072 / GBN, TOK / GBM), blk, 0, stream>>>(
        ln_s, qkvw_t, qkvb, (const bf16*)nullptr, qkv,
        nullptr, nullptr, nullptr, TOK, 3 * DIM, DIM);

    // 3. MFMA flash attention -> ctx (reuses ln slot)
    attn_mfma_kernel<<<dim3(SEQ / 64, BATCH * NH), blk, 0, stream>>>(qkv, mask, ln_s);

    // 4+5. attn_out = ctx @ attn_ow (no bias); resid = attn_out + attn_ob + x
    mgemm_kernel<bf16, 4><<<dim3(DIM / GBN, TOK / GBM), blk, 0, stream>>>(
        ln_s, attn_owt, (const float*)nullptr, (const bf16*)nullptr, attn_out,
        attn_ob, x, resid, TOK, DIM, DIM);

    // 6. ln2 = LN(resid)
    ln_kernel<<<TOK, blk, 0, stream>>>(resid, attn_nw, attn_nb, ln_s);

    // 7. inter = gelu(ln2 @ inter_w + inter_b)   [4096, 4096]
    mgemm_kernel<bf16, 1><<<dim3(IDIM / GBN, TOK / GBM), blk, 0, stream>>>(
        ln_s, inter_wt, inter_b, (const bf16*)nullptr, inter,
        nullptr, nullptr, nullptr, TOK, IDIM, DIM);

    // 8. inter = (attn_out @ inter_w1) * inter   (in-place gated product)
    mgemm_kernel<bf16, 2><<<dim3(IDIM / GBN, TOK / GBM), blk, 0, stream>>>(
        attn_out, inter_w1t, (const float*)nullptr, inter, inter,
        nullptr, nullptr, nullptr, TOK, IDIM, DIM);

    // 9. out = inter @ output_w + output_b + resid  (resid aliases out; each
    //    element read by its owning thread before write — safe)
    mgemm_kernel<float, 3><<<dim3(DIM / GBN, TOK / GBM), blk, 0, stream>>>(
        inter, output_wt, output_b, resid, out,
        nullptr, nullptr, nullptr, TOK, DIM, IDIM);
}